// Round 2
// 3350.229 us; speedup vs baseline: 1.0391x; 1.0391x over previous
//
#include <hip/hip_runtime.h>
#include <stdint.h>

typedef unsigned short u16;
typedef __bf16 bf16x8 __attribute__((ext_vector_type(8)));
typedef float  floatx4 __attribute__((ext_vector_type(4)));
typedef u16    ushort4v __attribute__((ext_vector_type(4)));
typedef u16    ushort8v __attribute__((ext_vector_type(8)));

#define B_ 2
#define S_ 2048
#define D_ 1024
#define N_ 4096
#define V_ 32000
#define R_ (B_ * S_)
#define L_ 6

__device__ __forceinline__ u16 f2bf(float f) {
  union { float f; uint32_t u; } v; v.f = f;
  uint32_t r = v.u + 0x7fffu + ((v.u >> 16) & 1u);
  return (u16)(r >> 16);
}
__device__ __forceinline__ float bf2f(u16 h) {
  union { uint32_t u; float f; } v; v.u = ((uint32_t)h) << 16;
  return v.f;
}

// async global->LDS, 16B per lane; LDS dest is wave-uniform base + lane*16
__device__ __forceinline__ void gload16(const u16* g, u16* l) {
  auto* gp = (__attribute__((address_space(1))) void*)const_cast<u16*>(g);
  auto* lp = (__attribute__((address_space(3))) void*)l;
  __builtin_amdgcn_global_load_lds(gp, lp, 16, 0, 0);
}

// ---------------------------------------------------------------- GEMM core
// C[M][N] = A[M][K] * BT[N][K]^T   (bf16 in, fp32 MFMA accumulate)
// m97 structure: 128x128 tile, BK=32, linear LDS, global_load_lds dwordx4.
// Block remap: row-fastest so co-resident blocks share the B tile (L3 reuse).
// MODE 0: store bf16   1: relu -> bf16   2: relu * Mul -> bf16   3: store f32
template<int MODE>
__global__ __launch_bounds__(256)
void gemm_bt(const u16* __restrict__ A, const u16* __restrict__ BT,
             void* __restrict__ Cv, const u16* __restrict__ Mul,
             int M, int N, int K, size_t sA, size_t sBT, size_t sC)
{
  __shared__ __align__(16) u16 As[128 * 32];
  __shared__ __align__(16) u16 Bs[128 * 32];

  const int tid  = threadIdx.x;
  const int lane = tid & 63;
  const int wave = tid >> 6;
  const int r = lane & 15;
  const int q = lane >> 4;
  const int wm = (wave >> 1) << 6;   // 2x2 waves, each 64x64
  const int wn = (wave & 1) << 6;

  // row-fastest block remap (bijective): consecutive bids share col-block bx
  const int nby = gridDim.y;
  const int bid = blockIdx.y * gridDim.x + blockIdx.x;
  const int bx  = bid / nby;
  const int by  = bid - bx * nby;
  const long m0 = (long)by * 128;
  const long n0 = (long)bx * 128;

  const u16* Ab = A  + (size_t)blockIdx.z * sA;
  const u16* Bb = BT + (size_t)blockIdx.z * sBT;

  // staging map: thread t covers 16B chunk t of the 8KB tile (rows 0..63),
  // and chunk t of rows 64..127. LDS is linear so chunk t lands at byte 16*t.
  const int srow = tid >> 2;           // 0..63
  const int scol = (tid & 3) << 3;     // 0,8,16,24
  const u16* a_src0 = Ab + (size_t)(m0 + srow) * K + scol;
  const u16* a_src1 = a_src0 + (size_t)64 * K;
  const u16* b_src0 = Bb + (size_t)(n0 + srow) * K + scol;
  const u16* b_src1 = b_src0 + (size_t)64 * K;
  // wave-uniform LDS bases: wave w covers bytes [1024w,1024w+1024) of each half
  u16* a_d0 = &As[wave * 512];
  u16* a_d1 = &As[2048 + wave * 512];
  u16* b_d0 = &Bs[wave * 512];
  u16* b_d1 = &Bs[2048 + wave * 512];

  const floatx4 zero = {0.f, 0.f, 0.f, 0.f};
  floatx4 acc[4][4];
#pragma unroll
  for (int i = 0; i < 4; ++i)
#pragma unroll
    for (int j = 0; j < 4; ++j) acc[i][j] = zero;

  for (int kt = 0; kt < K; kt += 32) {
    __syncthreads();                      // prev iter's ds_reads done
    gload16(a_src0 + kt, a_d0);
    gload16(a_src1 + kt, a_d1);
    gload16(b_src0 + kt, b_d0);
    gload16(b_src1 + kt, b_d1);
    __syncthreads();                      // vmcnt(0) drain: tiles resident

    bf16x8 af[4], bfr[4];
#pragma unroll
    for (int i = 0; i < 4; ++i)
      af[i]  = *(const bf16x8*)&As[(wm + i*16 + r) * 32 + (q << 3)];
#pragma unroll
    for (int j = 0; j < 4; ++j)
      bfr[j] = *(const bf16x8*)&Bs[(wn + j*16 + r) * 32 + (q << 3)];
#pragma unroll
    for (int i = 0; i < 4; ++i)
#pragma unroll
      for (int j = 0; j < 4; ++j)
        acc[i][j] = __builtin_amdgcn_mfma_f32_16x16x32_bf16(af[i], bfr[j], acc[i][j], 0, 0, 0);
  }

  // epilogue: C/D layout col = lane&15, row = (lane>>4)*4 + reg  [m89-verified]
  const long crow0 = m0 + wm + (q << 2);
  const long ccol0 = n0 + wn + r;
#pragma unroll
  for (int i = 0; i < 4; ++i) {
#pragma unroll
    for (int j = 0; j < 4; ++j) {
      const long col = ccol0 + j * 16;
#pragma unroll
      for (int ii = 0; ii < 4; ++ii) {
        const long row = crow0 + i * 16 + ii;
        float v = acc[i][j][ii];
        if (MODE == 1 || MODE == 2) v = fmaxf(v, 0.f);
        const size_t off = (size_t)row * N + col;
        if (MODE == 2) v *= bf2f(Mul[off]);
        if (MODE == 3) (((float*)Cv) + (size_t)blockIdx.z * sC)[off] = v;
        else           (((u16*)Cv)   + (size_t)blockIdx.z * sC)[off] = f2bf(v);
      }
    }
  }
}

// ------------------------------------------------- bf16 transpose (64x64 tiles)
__global__ __launch_bounds__(256)
void transpose_bf16(const u16* __restrict__ src, u16* __restrict__ dst, int R, int C)
{
  __shared__ __align__(16) u16 tile[64][68];
  const int t = threadIdx.x;
  const long r0 = (long)blockIdx.y * 64;
  const long c0 = (long)blockIdx.x * 64;
  const int tc = (t & 15) << 2;
  const int tr = t >> 4;
#pragma unroll
  for (int i = 0; i < 4; ++i) {
    const int rr = tr + (i << 4);
    *(ushort4v*)&tile[rr][tc] = *(const ushort4v*)(src + (size_t)(r0 + rr) * C + c0 + tc);
  }
  __syncthreads();
#pragma unroll
  for (int i = 0; i < 4; ++i) {
    const int cc = tr + (i << 4);
    ushort4v v;
#pragma unroll
    for (int j = 0; j < 4; ++j) v[j] = tile[tc + j][cc];
    *(ushort4v*)(dst + (size_t)(c0 + cc) * R + r0 + tc) = v;
  }
}

// -------------------------------------- fp32 -> bf16 transposed convert
__global__ __launch_bounds__(256)
void cvt_transpose(const float* __restrict__ src, u16* __restrict__ dst, int R, int C)
{
  __shared__ __align__(16) u16 tile[64][68];
  const int t = threadIdx.x;
  const long r0 = (long)blockIdx.y * 64;
  const long c0 = (long)blockIdx.x * 64;
  const int tc = (t & 15) << 2;
  const int tr = t >> 4;
#pragma unroll
  for (int i = 0; i < 4; ++i) {
    const int rr = tr + (i << 4);
    const float4 v = *(const float4*)(src + (size_t)(r0 + rr) * C + c0 + tc);
    ushort4v h = {f2bf(v.x), f2bf(v.y), f2bf(v.z), f2bf(v.w)};
    *(ushort4v*)&tile[rr][tc] = h;
  }
  __syncthreads();
#pragma unroll
  for (int i = 0; i < 4; ++i) {
    const int cc = tr + (i << 4);
    ushort4v v;
#pragma unroll
    for (int j = 0; j < 4; ++j) v[j] = tile[tc + j][cc];
    *(ushort4v*)(dst + (size_t)(c0 + cc) * R + r0 + tc) = v;
  }
}

// ------------------------------------------------- embedding gather
__global__ __launch_bounds__(256)
void embed_k(const int* __restrict__ idx, const float* __restrict__ emb,
             float* __restrict__ vf, u16* __restrict__ vb)
{
  const size_t row = blockIdx.x;
  const int t = threadIdx.x;
  const int id = idx[row];
  const float4 x = ((const float4*)(emb + (size_t)id * D_))[t];
  ((float4*)(vf + row * D_))[t] = x;
  ushort4v h = {f2bf(x.x), f2bf(x.y), f2bf(x.z), f2bf(x.w)};
  ((ushort4v*)(vb + row * D_))[t] = h;
}

// ------------------------------------------------- double layernorm (fp32)
__device__ __forceinline__ float block_sum(float v, float* red, int t) {
#pragma unroll
  for (int o = 32; o > 0; o >>= 1) v += __shfl_down(v, o, 64);
  __syncthreads();
  if ((t & 63) == 0) red[t >> 6] = v;
  __syncthreads();
  return red[0] + red[1] + red[2] + red[3];
}

__global__ __launch_bounds__(256)
void ln_k(const float* __restrict__ z, float* __restrict__ vf, u16* __restrict__ vb)
{
  __shared__ float red[4];
  const int t = threadIdx.x;
  const size_t row = blockIdx.x;
  const float4 zv = ((const float4*)(z + row * D_))[t];
  float s = zv.x + zv.y + zv.z + zv.w;
  const float mean = block_sum(s, red, t) * (1.0f / D_);
  float4 d;
  d.x = zv.x - mean; d.y = zv.y - mean; d.z = zv.z - mean; d.w = zv.w - mean;
  float s2 = d.x*d.x + d.y*d.y + d.z*d.z + d.w*d.w;
  const float var = block_sum(s2, red, t) * (1.0f / D_);
  const float inv = rsqrtf(var + 1e-5f);
  const float4 vv = ((const float4*)(vf + row * D_))[t];
  float4 w;
  w.x = vv.x + d.x * inv; w.y = vv.y + d.y * inv;
  w.z = vv.z + d.z * inv; w.w = vv.w + d.w * inv;
  float sw = w.x + w.y + w.z + w.w;
  const float mean2 = block_sum(sw, red, t) * (1.0f / D_);
  float4 d2;
  d2.x = w.x - mean2; d2.y = w.y - mean2; d2.z = w.z - mean2; d2.w = w.w - mean2;
  float s22 = d2.x*d2.x + d2.y*d2.y + d2.z*d2.z + d2.w*d2.w;
  const float var2 = block_sum(s22, red, t) * (1.0f / D_);
  const float inv2 = rsqrtf(var2 + 1e-5f);
  float4 o;
  o.x = d2.x * inv2; o.y = d2.y * inv2; o.z = d2.z * inv2; o.w = d2.w * inv2;
  ((float4*)(vf + row * D_))[t] = o;
  ushort4v h = {f2bf(o.x), f2bf(o.y), f2bf(o.z), f2bf(o.w)};
  ((ushort4v*)(vb + row * D_))[t] = h;
}

// =================================================================== launch
extern "C" void kernel_launch(void* const* d_in, const int* in_sizes, int n_in,
                              void* d_out, int out_size, void* d_ws, size_t ws_size,
                              hipStream_t stream)
{
  const int*   inp = (const int*)d_in[0];
  const float* emb = (const float*)d_in[1];
  const float* Dx  = (const float*)d_in[2];
  const float* Dy  = (const float*)d_in[3];
  const float* E   = (const float*)d_in[4];
  const float* ro  = (const float*)d_in[5];
  float* out = (float*)d_out;

  char* p = (char*)d_ws;
  auto take = [&](size_t n) { char* q = p; p += (n + 255) & ~(size_t)255; return q; };
  float* vf  = (float*)take((size_t)R_ * D_ * 4);
  float* zf  = (float*)take((size_t)R_ * D_ * 4);
  u16* vb    = (u16*)take((size_t)R_ * D_ * 2);
  u16* vbT   = (u16*)take((size_t)R_ * D_ * 2);
  u16* xb    = (u16*)take((size_t)R_ * N_ * 2);
  u16* xbT   = (u16*)take((size_t)R_ * N_ * 2);
  u16* yb    = (u16*)take((size_t)R_ * N_ * 2);
  u16* kvT   = (u16*)take((size_t)B_ * D_ * N_ * 2);
  u16* ab    = (u16*)take((size_t)R_ * D_ * 2);
  u16* DxT   = (u16*)take((size_t)D_ * N_ * 2);
  u16* DyT   = (u16*)take((size_t)D_ * N_ * 2);
  u16* ET    = (u16*)take((size_t)D_ * N_ * 2);
  u16* roT   = (u16*)take((size_t)D_ * V_ * 2);

  const dim3 blk(256);

  // weights -> bf16, transposed to [N][K] form
  cvt_transpose<<<dim3(N_/64, D_/64), blk, 0, stream>>>(Dx, DxT, D_, N_);
  cvt_transpose<<<dim3(N_/64, D_/64), blk, 0, stream>>>(Dy, DyT, D_, N_);
  cvt_transpose<<<dim3(D_/64, N_/64), blk, 0, stream>>>(E,  ET,  N_, D_);
  cvt_transpose<<<dim3(V_/64, D_/64), blk, 0, stream>>>(ro, roT, D_, V_);

  embed_k<<<dim3(R_), blk, 0, stream>>>(inp, emb, vf, vb);
  for (int b = 0; b < B_; ++b)
    transpose_bf16<<<dim3(D_/64, S_/64), blk, 0, stream>>>(
        vb + (size_t)b*S_*D_, vbT + (size_t)b*D_*S_, S_, D_);

  for (int l = 0; l < L_; ++l) {
    // x = relu(v @ Dx)            [R_, N_]
    gemm_bt<1><<<dim3(N_/128, R_/128, 1), blk, 0, stream>>>(
        vb, DxT, xb, nullptr, R_, N_, D_, 0, 0, 0);
    // xT per batch               [N_, S_]
    for (int b = 0; b < B_; ++b)
      transpose_bf16<<<dim3(N_/64, S_/64), blk, 0, stream>>>(
          xb + (size_t)b*S_*N_, xbT + (size_t)b*N_*S_, S_, N_);
    // kvT[b] = v[b]^T @ x[b]      [D_, N_]   (A = vT, BT = xT)
    gemm_bt<0><<<dim3(N_/128, D_/128, B_), blk, 0, stream>>>(
        vbT, xbT, kvT, nullptr, D_, N_, S_,
        (size_t)D_*S_, (size_t)N_*S_, (size_t)D_*N_);
    // a[b] = x[b] @ kv[b]         [S_, D_]   (BT = kvT)
    gemm_bt<0><<<dim3(D_/128, S_/128, B_), blk, 0, stream>>>(
        xb, kvT, ab, nullptr, S_, D_, N_,
        (size_t)S_*N_, (size_t)D_*N_, (size_t)S_*D_);
    // y = relu(a @ Dy) * x        [R_, N_]
    gemm_bt<2><<<dim3(N_/128, R_/128, 1), blk, 0, stream>>>(
        ab, DyT, yb, xb, R_, N_, D_, 0, 0, 0);
    // z = y @ E (fp32)            [R_, D_]
    gemm_bt<3><<<dim3(D_/128, R_/128, 1), blk, 0, stream>>>(
        yb, ET, zf, nullptr, R_, D_, N_, 0, 0, 0);
    // v = LN(v + LN(z)) (fp32 master, bf16 shadow)
    ln_k<<<dim3(R_), blk, 0, stream>>>(zf, vf, vb);
    for (int b = 0; b < B_; ++b)
      transpose_bf16<<<dim3(D_/64, S_/64), blk, 0, stream>>>(
          vb + (size_t)b*S_*D_, vbT + (size_t)b*D_*S_, S_, D_);
  }

  // out = v @ readout (fp32)      [R_, V_]
  gemm_bt<3><<<dim3(V_/128, R_/128, 1), blk, 0, stream>>>(
      vb, roT, out, nullptr, R_, V_, D_, 0, 0, 0);
}

// Round 3
// 3065.618 us; speedup vs baseline: 1.1356x; 1.0928x over previous
//
#include <hip/hip_runtime.h>
#include <stdint.h>

typedef unsigned short u16;
typedef __bf16 bf16x8 __attribute__((ext_vector_type(8)));
typedef float  floatx4 __attribute__((ext_vector_type(4)));
typedef u16    ushort4v __attribute__((ext_vector_type(4)));
typedef u16    ushort8v __attribute__((ext_vector_type(8)));

#define B_ 2
#define S_ 2048
#define D_ 1024
#define N_ 4096
#define V_ 32000
#define R_ (B_ * S_)
#define L_ 6

__device__ __forceinline__ u16 f2bf(float f) {
  union { float f; uint32_t u; } v; v.f = f;
  uint32_t r = v.u + 0x7fffu + ((v.u >> 16) & 1u);
  return (u16)(r >> 16);
}
__device__ __forceinline__ float bf2f(u16 h) {
  union { uint32_t u; float f; } v; v.u = ((uint32_t)h) << 16;
  return v.f;
}

// async global->LDS, 16B per lane; LDS dest is wave-uniform base + lane*16
__device__ __forceinline__ void gload16(const u16* g, u16* l) {
  auto* gp = (__attribute__((address_space(1))) void*)const_cast<u16*>(g);
  auto* lp = (__attribute__((address_space(3))) void*)l;
  __builtin_amdgcn_global_load_lds(gp, lp, 16, 0, 0);
}

// ================================================================ gemm256
// C[M][N] = A[M][K]*BT[N][K]^T. 256x256 tile, 8 waves (2M x 4N), BK=32,
// double-buffered LDS (64KB), counted vmcnt(4) pipeline, XOR chunk swizzle.
// Swizzle: LDS slot s of row holds global 16B-chunk  c = s ^ ((row>>1)&3);
// applied on the global source (gload_lds writes linearly) and on ds_read.
// MODE 1: relu->bf16  2: relu*Mul->bf16  3: store f32
template<int MODE>
__global__ __launch_bounds__(512, 2)
void gemm256(const u16* __restrict__ A, const u16* __restrict__ BT,
             void* __restrict__ Cv, const u16* __restrict__ Mul,
             int M, int N, int K, size_t sA, size_t sBT, size_t sC)
{
  __shared__ __align__(16) u16 SH[2][2][8192];   // [buf][A|B][256*32]

  const int tid  = threadIdx.x;
  const int lane = tid & 63;
  const int wave = tid >> 6;          // 0..7
  const int r = lane & 15;
  const int q = lane >> 4;
  const int wm = (wave >> 2) << 7;    // 0 or 128
  const int wn = (wave & 3) << 6;     // 0,64,128,192

  // row-fastest block remap: consecutive bids share the B panel (L2/L3 reuse)
  const int nby = gridDim.y;
  const int bid = blockIdx.y * gridDim.x + blockIdx.x;
  const int bx  = bid / nby;
  const int by  = bid - bx * nby;
  const long m0 = (long)by * 256;
  const long n0 = (long)bx * 256;

  const u16* Ab = A  + (size_t)blockIdx.z * sA;
  const u16* Bb = BT + (size_t)blockIdx.z * sBT;

  // staging: round j covers rows 128j..128j+127; thread t -> (row=t>>2, slot=t&3)
  // source chunk c = slot ^ ((row>>1)&3)  (inverse of read swizzle)
  const int srow = tid >> 2;                                  // 0..127
  const int scol = (((tid & 3) ^ ((srow >> 1) & 3)) << 3);    // elems
  const u16* a_s0 = Ab + (size_t)(m0 + srow) * K + scol;
  const u16* a_s1 = a_s0 + (size_t)128 * K;
  const u16* b_s0 = Bb + (size_t)(n0 + srow) * K + scol;
  const u16* b_s1 = b_s0 + (size_t)128 * K;
  const int dst0 = wave * 512;            // u16 offset, round 0
  const int dst1 = 4096 + wave * 512;     // round 1

  // read side: chunk' = q ^ ((r>>1)&3)
  const int cp = (q ^ ((r >> 1) & 3)) << 3;
  const int abase = (wm + r) * 32 + cp;
  const int bbase = (wn + r) * 32 + cp;

  const floatx4 zero = {0.f, 0.f, 0.f, 0.f};
  floatx4 acc[8][4];
#pragma unroll
  for (int i = 0; i < 8; ++i)
#pragma unroll
    for (int j = 0; j < 4; ++j) acc[i][j] = zero;

  const int nt = K >> 5;
  // prologue: stage K-tile 0 into buf 0
  gload16(a_s0, &SH[0][0][dst0]);
  gload16(a_s1, &SH[0][0][dst1]);
  gload16(b_s0, &SH[0][1][dst0]);
  gload16(b_s1, &SH[0][1][dst1]);

  int p = 0;
  for (int t = 0; t < nt; ++t) {
    const int kt = (t + 1) << 5;
    if (t + 1 < nt) {                       // stage next tile into buf p^1
      gload16(a_s0 + kt, &SH[p ^ 1][0][dst0]);
      gload16(a_s1 + kt, &SH[p ^ 1][0][dst1]);
      gload16(b_s0 + kt, &SH[p ^ 1][1][dst0]);
      gload16(b_s1 + kt, &SH[p ^ 1][1][dst1]);
      asm volatile("s_waitcnt vmcnt(4)" ::: "memory");  // buf p landed; 4 in flight
    } else {
      asm volatile("s_waitcnt vmcnt(0)" ::: "memory");
    }
    __builtin_amdgcn_s_barrier();           // all waves' buf p parts visible
    __builtin_amdgcn_sched_barrier(0);
    asm volatile("" ::: "memory");

    const u16* As = SH[p][0];
    const u16* Bs = SH[p][1];
    bf16x8 bfr[4];
#pragma unroll
    for (int j = 0; j < 4; ++j)
      bfr[j] = *(const bf16x8*)&Bs[bbase + j * 512];
#pragma unroll
    for (int h = 0; h < 2; ++h) {
      bf16x8 af[4];
#pragma unroll
      for (int i2 = 0; i2 < 4; ++i2)
        af[i2] = *(const bf16x8*)&As[abase + (h * 4 + i2) * 512];
#pragma unroll
      for (int i2 = 0; i2 < 4; ++i2)
#pragma unroll
        for (int j = 0; j < 4; ++j)
          acc[h * 4 + i2][j] = __builtin_amdgcn_mfma_f32_16x16x32_bf16(
              af[i2], bfr[j], acc[h * 4 + i2][j], 0, 0, 0);
    }
    asm volatile("s_waitcnt lgkmcnt(0)" ::: "memory");  // my ds_reads of buf p done
    __builtin_amdgcn_s_barrier();           // everyone done reading buf p
    __builtin_amdgcn_sched_barrier(0);
    asm volatile("" ::: "memory");
    p ^= 1;
  }

  // epilogue: C/D layout col = lane&15, row = (lane>>4)*4 + reg
  const long crow0 = m0 + wm + (q << 2);
  const long ccol0 = n0 + wn + r;
#pragma unroll
  for (int f = 0; f < 8; ++f) {
#pragma unroll
    for (int j = 0; j < 4; ++j) {
      const long col = ccol0 + j * 16;
#pragma unroll
      for (int ii = 0; ii < 4; ++ii) {
        const long row = crow0 + f * 16 + ii;
        float v = acc[f][j][ii];
        if (MODE == 1 || MODE == 2) v = fmaxf(v, 0.f);
        const size_t off = (size_t)row * N + col;
        if (MODE == 2) v *= bf2f(Mul[off]);
        if (MODE == 3) (((float*)Cv) + (size_t)blockIdx.z * sC)[off] = v;
        else           (((u16*)Cv)   + (size_t)blockIdx.z * sC)[off] = f2bf(v);
      }
    }
  }
}

// ---------------------------------------------------------------- GEMM core
// 128x128 tile, BK=32, linear LDS + same XOR chunk swizzle, gload_lds, 2 barriers.
// Used for the small-grid gemms (kv, a, z) where 256^2 tiles would starve CUs.
// MODE 0: store bf16   3: store f32
template<int MODE>
__global__ __launch_bounds__(256)
void gemm_bt(const u16* __restrict__ A, const u16* __restrict__ BT,
             void* __restrict__ Cv, const u16* __restrict__ Mul,
             int M, int N, int K, size_t sA, size_t sBT, size_t sC)
{
  __shared__ __align__(16) u16 As[128 * 32];
  __shared__ __align__(16) u16 Bs[128 * 32];

  const int tid  = threadIdx.x;
  const int lane = tid & 63;
  const int wave = tid >> 6;
  const int r = lane & 15;
  const int q = lane >> 4;
  const int wm = (wave >> 1) << 6;   // 2x2 waves, each 64x64
  const int wn = (wave & 1) << 6;

  const int nby = gridDim.y;
  const int bid = blockIdx.y * gridDim.x + blockIdx.x;
  const int bx  = bid / nby;
  const int by  = bid - bx * nby;
  const long m0 = (long)by * 128;
  const long n0 = (long)bx * 128;

  const u16* Ab = A  + (size_t)blockIdx.z * sA;
  const u16* Bb = BT + (size_t)blockIdx.z * sBT;

  const int srow = tid >> 2;           // 0..63
  const int scol = (((tid & 3) ^ ((srow >> 1) & 3)) << 3);
  const u16* a_src0 = Ab + (size_t)(m0 + srow) * K + scol;
  const u16* a_src1 = a_src0 + (size_t)64 * K;
  const u16* b_src0 = Bb + (size_t)(n0 + srow) * K + scol;
  const u16* b_src1 = b_src0 + (size_t)64 * K;
  u16* a_d0 = &As[wave * 512];
  u16* a_d1 = &As[2048 + wave * 512];
  u16* b_d0 = &Bs[wave * 512];
  u16* b_d1 = &Bs[2048 + wave * 512];

  const int cp = (q ^ ((r >> 1) & 3)) << 3;

  const floatx4 zero = {0.f, 0.f, 0.f, 0.f};
  floatx4 acc[4][4];
#pragma unroll
  for (int i = 0; i < 4; ++i)
#pragma unroll
    for (int j = 0; j < 4; ++j) acc[i][j] = zero;

  for (int kt = 0; kt < K; kt += 32) {
    __syncthreads();
    gload16(a_src0 + kt, a_d0);
    gload16(a_src1 + kt, a_d1);
    gload16(b_src0 + kt, b_d0);
    gload16(b_src1 + kt, b_d1);
    __syncthreads();

    bf16x8 af[4], bfr[4];
#pragma unroll
    for (int i = 0; i < 4; ++i)
      af[i]  = *(const bf16x8*)&As[(wm + i*16 + r) * 32 + cp];
#pragma unroll
    for (int j = 0; j < 4; ++j)
      bfr[j] = *(const bf16x8*)&Bs[(wn + j*16 + r) * 32 + cp];
#pragma unroll
    for (int i = 0; i < 4; ++i)
#pragma unroll
      for (int j = 0; j < 4; ++j)
        acc[i][j] = __builtin_amdgcn_mfma_f32_16x16x32_bf16(af[i], bfr[j], acc[i][j], 0, 0, 0);
  }

  const long crow0 = m0 + wm + (q << 2);
  const long ccol0 = n0 + wn + r;
#pragma unroll
  for (int i = 0; i < 4; ++i) {
#pragma unroll
    for (int j = 0; j < 4; ++j) {
      const long col = ccol0 + j * 16;
#pragma unroll
      for (int ii = 0; ii < 4; ++ii) {
        const long row = crow0 + i * 16 + ii;
        float v = acc[i][j][ii];
        if (MODE == 1 || MODE == 2) v = fmaxf(v, 0.f);
        const size_t off = (size_t)row * N + col;
        if (MODE == 2) v *= bf2f(Mul[off]);
        if (MODE == 3) (((float*)Cv) + (size_t)blockIdx.z * sC)[off] = v;
        else           (((u16*)Cv)   + (size_t)blockIdx.z * sC)[off] = f2bf(v);
      }
    }
  }
}

// ------------------------------------------------- bf16 transpose (64x64 tiles)
__global__ __launch_bounds__(256)
void transpose_bf16(const u16* __restrict__ src, u16* __restrict__ dst, int R, int C)
{
  __shared__ __align__(16) u16 tile[64][68];
  const int t = threadIdx.x;
  const long r0 = (long)blockIdx.y * 64;
  const long c0 = (long)blockIdx.x * 64;
  const int tc = (t & 15) << 2;
  const int tr = t >> 4;
#pragma unroll
  for (int i = 0; i < 4; ++i) {
    const int rr = tr + (i << 4);
    *(ushort4v*)&tile[rr][tc] = *(const ushort4v*)(src + (size_t)(r0 + rr) * C + c0 + tc);
  }
  __syncthreads();
#pragma unroll
  for (int i = 0; i < 4; ++i) {
    const int cc = tr + (i << 4);
    ushort4v v;
#pragma unroll
    for (int j = 0; j < 4; ++j) v[j] = tile[tc + j][cc];
    *(ushort4v*)(dst + (size_t)(c0 + cc) * R + r0 + tc) = v;
  }
}

// -------------------------------------- fp32 -> bf16 transposed convert
__global__ __launch_bounds__(256)
void cvt_transpose(const float* __restrict__ src, u16* __restrict__ dst, int R, int C)
{
  __shared__ __align__(16) u16 tile[64][68];
  const int t = threadIdx.x;
  const long r0 = (long)blockIdx.y * 64;
  const long c0 = (long)blockIdx.x * 64;
  const int tc = (t & 15) << 2;
  const int tr = t >> 4;
#pragma unroll
  for (int i = 0; i < 4; ++i) {
    const int rr = tr + (i << 4);
    const float4 v = *(const float4*)(src + (size_t)(r0 + rr) * C + c0 + tc);
    ushort4v h = {f2bf(v.x), f2bf(v.y), f2bf(v.z), f2bf(v.w)};
    *(ushort4v*)&tile[rr][tc] = h;
  }
  __syncthreads();
#pragma unroll
  for (int i = 0; i < 4; ++i) {
    const int cc = tr + (i << 4);
    ushort4v v;
#pragma unroll
    for (int j = 0; j < 4; ++j) v[j] = tile[tc + j][cc];
    *(ushort4v*)(dst + (size_t)(c0 + cc) * R + r0 + tc) = v;
  }
}

// ------------------------------------------------- embedding gather
__global__ __launch_bounds__(256)
void embed_k(const int* __restrict__ idx, const float* __restrict__ emb,
             float* __restrict__ vf, u16* __restrict__ vb)
{
  const size_t row = blockIdx.x;
  const int t = threadIdx.x;
  const int id = idx[row];
  const float4 x = ((const float4*)(emb + (size_t)id * D_))[t];
  ((float4*)(vf + row * D_))[t] = x;
  ushort4v h = {f2bf(x.x), f2bf(x.y), f2bf(x.z), f2bf(x.w)};
  ((ushort4v*)(vb + row * D_))[t] = h;
}

// ------------------------------------------------- double layernorm (fp32)
__device__ __forceinline__ float block_sum(float v, float* red, int t) {
#pragma unroll
  for (int o = 32; o > 0; o >>= 1) v += __shfl_down(v, o, 64);
  __syncthreads();
  if ((t & 63) == 0) red[t >> 6] = v;
  __syncthreads();
  return red[0] + red[1] + red[2] + red[3];
}

__global__ __launch_bounds__(256)
void ln_k(const float* __restrict__ z, float* __restrict__ vf, u16* __restrict__ vb)
{
  __shared__ float red[4];
  const int t = threadIdx.x;
  const size_t row = blockIdx.x;
  const float4 zv = ((const float4*)(z + row * D_))[t];
  float s = zv.x + zv.y + zv.z + zv.w;
  const float mean = block_sum(s, red, t) * (1.0f / D_);
  float4 d;
  d.x = zv.x - mean; d.y = zv.y - mean; d.z = zv.z - mean; d.w = zv.w - mean;
  float s2 = d.x*d.x + d.y*d.y + d.z*d.z + d.w*d.w;
  const float var = block_sum(s2, red, t) * (1.0f / D_);
  const float inv = rsqrtf(var + 1e-5f);
  const float4 vv = ((const float4*)(vf + row * D_))[t];
  float4 w;
  w.x = vv.x + d.x * inv; w.y = vv.y + d.y * inv;
  w.z = vv.z + d.z * inv; w.w = vv.w + d.w * inv;
  float sw = w.x + w.y + w.z + w.w;
  const float mean2 = block_sum(sw, red, t) * (1.0f / D_);
  float4 d2;
  d2.x = w.x - mean2; d2.y = w.y - mean2; d2.z = w.z - mean2; d2.w = w.w - mean2;
  float s22 = d2.x*d2.x + d2.y*d2.y + d2.z*d2.z + d2.w*d2.w;
  const float var2 = block_sum(s22, red, t) * (1.0f / D_);
  const float inv2 = rsqrtf(var2 + 1e-5f);
  float4 o;
  o.x = d2.x * inv2; o.y = d2.y * inv2; o.z = d2.z * inv2; o.w = d2.w * inv2;
  ((float4*)(vf + row * D_))[t] = o;
  ushort4v h = {f2bf(o.x), f2bf(o.y), f2bf(o.z), f2bf(o.w)};
  ((ushort4v*)(vb + row * D_))[t] = h;
}

// =================================================================== launch
extern "C" void kernel_launch(void* const* d_in, const int* in_sizes, int n_in,
                              void* d_out, int out_size, void* d_ws, size_t ws_size,
                              hipStream_t stream)
{
  const int*   inp = (const int*)d_in[0];
  const float* emb = (const float*)d_in[1];
  const float* Dx  = (const float*)d_in[2];
  const float* Dy  = (const float*)d_in[3];
  const float* E   = (const float*)d_in[4];
  const float* ro  = (const float*)d_in[5];
  float* out = (float*)d_out;

  char* p = (char*)d_ws;
  auto take = [&](size_t n) { char* q = p; p += (n + 255) & ~(size_t)255; return q; };
  float* vf  = (float*)take((size_t)R_ * D_ * 4);
  float* zf  = (float*)take((size_t)R_ * D_ * 4);
  u16* vb    = (u16*)take((size_t)R_ * D_ * 2);
  u16* vbT   = (u16*)take((size_t)R_ * D_ * 2);
  u16* xb    = (u16*)take((size_t)R_ * N_ * 2);
  u16* xbT   = (u16*)take((size_t)R_ * N_ * 2);
  u16* yb    = (u16*)take((size_t)R_ * N_ * 2);
  u16* kvT   = (u16*)take((size_t)B_ * D_ * N_ * 2);
  u16* ab    = (u16*)take((size_t)R_ * D_ * 2);
  u16* DxT   = (u16*)take((size_t)D_ * N_ * 2);
  u16* DyT   = (u16*)take((size_t)D_ * N_ * 2);
  u16* ET    = (u16*)take((size_t)D_ * N_ * 2);
  u16* roT   = (u16*)take((size_t)D_ * V_ * 2);

  const dim3 blk(256);
  const dim3 blk512(512);

  // weights -> bf16, transposed to [N][K] form
  cvt_transpose<<<dim3(N_/64, D_/64), blk, 0, stream>>>(Dx, DxT, D_, N_);
  cvt_transpose<<<dim3(N_/64, D_/64), blk, 0, stream>>>(Dy, DyT, D_, N_);
  cvt_transpose<<<dim3(D_/64, N_/64), blk, 0, stream>>>(E,  ET,  N_, D_);
  cvt_transpose<<<dim3(V_/64, D_/64), blk, 0, stream>>>(ro, roT, D_, V_);

  embed_k<<<dim3(R_), blk, 0, stream>>>(inp, emb, vf, vb);
  for (int b = 0; b < B_; ++b)
    transpose_bf16<<<dim3(D_/64, S_/64), blk, 0, stream>>>(
        vb + (size_t)b*S_*D_, vbT + (size_t)b*D_*S_, S_, D_);

  for (int l = 0; l < L_; ++l) {
    // x = relu(v @ Dx)            [R_, N_]   (256^2 core)
    gemm256<1><<<dim3(N_/256, R_/256, 1), blk512, 0, stream>>>(
        vb, DxT, xb, nullptr, R_, N_, D_, 0, 0, 0);
    // xT per batch               [N_, S_]
    for (int b = 0; b < B_; ++b)
      transpose_bf16<<<dim3(N_/64, S_/64), blk, 0, stream>>>(
          xb + (size_t)b*S_*N_, xbT + (size_t)b*N_*S_, S_, N_);
    // kvT[b] = v[b]^T @ x[b]      [D_, N_]   (A = vT, BT = xT)
    gemm_bt<0><<<dim3(N_/128, D_/128, B_), blk, 0, stream>>>(
        vbT, xbT, kvT, nullptr, D_, N_, S_,
        (size_t)D_*S_, (size_t)N_*S_, (size_t)D_*N_);
    // a[b] = x[b] @ kv[b]         [S_, D_]   (BT = kvT)
    gemm_bt<0><<<dim3(D_/128, S_/128, B_), blk, 0, stream>>>(
        xb, kvT, ab, nullptr, S_, D_, N_,
        (size_t)S_*N_, (size_t)D_*N_, (size_t)S_*D_);
    // y = relu(a @ Dy) * x        [R_, N_]   (256^2 core)
    gemm256<2><<<dim3(N_/256, R_/256, 1), blk512, 0, stream>>>(
        ab, DyT, yb, xb, R_, N_, D_, 0, 0, 0);
    // z = y @ E (fp32)            [R_, D_]
    gemm_bt<3><<<dim3(D_/128, R_/128, 1), blk, 0, stream>>>(
        yb, ET, zf, nullptr, R_, D_, N_, 0, 0, 0);
    // v = LN(v + LN(z)) (fp32 master, bf16 shadow)
    ln_k<<<dim3(R_), blk, 0, stream>>>(zf, vf, vb);
    for (int b = 0; b < B_; ++b)
      transpose_bf16<<<dim3(D_/64, S_/64), blk, 0, stream>>>(
          vb + (size_t)b*S_*D_, vbT + (size_t)b*D_*S_, S_, D_);
  }

  // out = v @ readout (fp32)      [R_, V_]   (256^2 core)
  gemm256<3><<<dim3(V_/256, R_/256, 1), blk512, 0, stream>>>(
      vb, roT, out, nullptr, R_, V_, D_, 0, 0, 0);
}